// Round 1
// baseline (84.240 us; speedup 1.0000x reference)
//
#include <hip/hip_runtime.h>
#include <math.h>

// Problem constants
#define NPIX   (512 * 3072)     // 1,572,864 pixels (= flat x length)
#define NCLS   10
#define NLAYER 3

typedef float v2f __attribute__((ext_vector_type(2)));
typedef float v4f __attribute__((ext_vector_type(4)));

// sin/cos(k*pi/8), k=0..7  (half-angles of the 8 DFT sample points x_k = k*pi/4)
__device__ __constant__ float SHK[8] = {
    0.0f, 0.38268343236f, 0.70710678119f, 0.92387953251f,
    1.0f, 0.92387953251f, 0.70710678119f, 0.38268343236f };
__device__ __constant__ float CHK[8] = {
    1.0f, 0.92387953251f, 0.70710678119f, 0.38268343236f,
    0.0f, -0.38268343236f, -0.70710678119f, -0.92387953251f };
// cos/sin(i*pi/4), i=0..7 (DFT twiddles)
__device__ __constant__ float CT8[8] = {
    1.0f, 0.70710678119f, 0.0f, -0.70710678119f,
    -1.0f, -0.70710678119f, 0.0f, 0.70710678119f };
__device__ __constant__ float ST8[8] = {
    0.0f, 0.70710678119f, 1.0f, 0.70710678119f,
    0.0f, -0.70710678119f, -1.0f, -0.70710678119f };

// ---------------------------------------------------------------------------
// |s0(x)|^2 of the 3-layer circuit is band-limited to the 3rd harmonic:
// out[p][c] = a0 + sum_m am cos(mx) + bm sin(mx). 7 coefficients/class,
// recovered exactly by an 8-point DFT of the circuit sampled at x_k = k*pi/4.
//
// SPLIT (this round): the 70 coefficients are grid-uniform, so compute them
// ONCE in a 1-block kernel into d_ws instead of redundantly in all 3072
// blocks (which cost 2 extra barriers + 70 LDS-broadcast reads per wave and
// capped residency at 7 blocks/CU).
// ---------------------------------------------------------------------------
__global__ __launch_bounds__(128) void coef_kernel(const float* __restrict__ params,
                                                   float* __restrict__ coef) {
    __shared__ float y[80];                 // y[c*8 + k]
    const int t = threadIdx.x;

    if (t < NCLS * 8) {
        const int c = t >> 3;
        const int k = t & 7;
        const float shx = SHK[k], chx = CHK[k];   // Ry(x_k) half-angle sin/cos

        float s0r = 1.f, s0i = 0.f, s1r = 0.f, s1i = 0.f;

        #pragma unroll
        for (int l = 0; l < NLAYER; ++l) {
            // Ry(x_k)
            {
                float n0r = chx * s0r - shx * s1r;
                float n0i = chx * s0i - shx * s1i;
                float n1r = shx * s0r + chx * s1r;
                float n1i = shx * s0i + chx * s1i;
                s0r = n0r; s0i = n0i; s1r = n1r; s1i = n1i;
            }
            // Rz(g0): s0 *= e^{-i th}, s1 *= e^{+i th}
            {
                float th = 0.5f * params[(c * NLAYER + l) * 3 + 0];
                float st, ct;
                __sincosf(th, &st, &ct);
                float n0r = s0r * ct + s0i * st;
                float n0i = s0i * ct - s0r * st;
                float n1r = s1r * ct - s1i * st;
                float n1i = s1i * ct + s1r * st;
                s0r = n0r; s0i = n0i; s1r = n1r; s1i = n1i;
            }
            // Ry(g1)
            {
                float th = 0.5f * params[(c * NLAYER + l) * 3 + 1];
                float sh, ch;
                __sincosf(th, &sh, &ch);
                float n0r = ch * s0r - sh * s1r;
                float n0i = ch * s0i - sh * s1i;
                float n1r = sh * s0r + ch * s1r;
                float n1i = sh * s0i + ch * s1i;
                s0r = n0r; s0i = n0i; s1r = n1r; s1i = n1i;
            }
            // Rz(g2)
            {
                float th = 0.5f * params[(c * NLAYER + l) * 3 + 2];
                float st, ct;
                __sincosf(th, &st, &ct);
                float n0r = s0r * ct + s0i * st;
                float n0i = s0i * ct - s0r * st;
                float n1r = s1r * ct - s1i * st;
                float n1i = s1i * ct + s1r * st;
                s0r = n0r; s0i = n0i; s1r = n1r; s1i = n1i;
            }
        }
        y[t] = s0r * s0r + s0i * s0i;       // t == c*8 + k
    }
    __syncthreads();

    // table-weighted 8-point DFT -> 7 coefficients/class
    if (t < NCLS * 7) {
        const int c = t / 7;
        const int j = t % 7;
        float acc = 0.f;
        #pragma unroll
        for (int k = 0; k < 8; ++k) {
            float w;
            if (j == 0)       w = 0.125f;
            else if (j <= 3)  w = 0.25f * CT8[(j * k) & 7];
            else              w = 0.25f * ST8[((j - 3) * k) & 7];
            acc += y[c * 8 + k] * w;
        }
        coef[t] = acc;                      // coef[c*7 + j] in workspace
    }
}

// ---------------------------------------------------------------------------
// Hot streaming kernel: pure load->reconstruct->store.
// coefs come from global with uniform addresses -> readfirstlane pins them
// to SGPRs (L1-hit after the first block per CU). One barrier total.
// LDS = exactly 20 KB -> 8 blocks/CU (32 waves/CU, max occupancy).
// ---------------------------------------------------------------------------
__global__ __launch_bounds__(256) void pix_kernel(const float* __restrict__ x,
                                                  const float* __restrict__ coef,
                                                  float* __restrict__ out) {
    __shared__ __align__(16) float tile[5120];  // 20 KB output staging

    const int t = threadIdx.x;
    const int g = blockIdx.x * 256 + t;         // pixel-pair index

    // coalesced input load, issued early (read-once -> nontemporal)
    const v2f xv = __builtin_nontemporal_load(&((const v2f*)x)[g]);

    // block-uniform coefficients -> SGPRs (frees ~70 VGPRs)
    float cf[NCLS * 7];
    #pragma unroll
    for (int i = 0; i < NCLS * 7; ++i)
        cf[i] = __int_as_float(
            __builtin_amdgcn_readfirstlane(__float_as_int(coef[i])));

    const float px[2] = {xv.x, xv.y};
    float r[20];
    #pragma unroll
    for (int p = 0; p < 2; ++p) {
        float s1, c1;
        __sincosf(px[p], &s1, &c1);             // x in [0,1): fast path OK
        const float c2 = 2.f * c1 * c1 - 1.f;
        const float s2 = 2.f * s1 * c1;
        const float c3 = c1 * c2 - s1 * s2;
        const float s3 = s1 * c2 + c1 * s2;
        #pragma unroll
        for (int c = 0; c < NCLS; ++c) {
            const float* f = &cf[c * 7];
            r[p * 10 + c] = f[0] + f[1] * c1 + f[2] * c2 + f[3] * c3
                                 + f[4] * s1 + f[5] * s2 + f[6] * s3;
        }
    }

    // stage to LDS: 5x ds_write_b128 at 80 B lane stride (<=2-way alias, free)
    v4f* wb = (v4f*)&tile[t * 20];
    #pragma unroll
    for (int i = 0; i < 5; ++i) wb[i] = ((const v4f*)r)[i];

    __syncthreads();

    // stream out: contiguous wave-wide nontemporal float4 stores
    v4f* o4 = (v4f*)out + (size_t)blockIdx.x * 1280;   // 5120 floats/block
    const v4f* l4 = (const v4f*)tile;
    #pragma unroll
    for (int i = 0; i < 5; ++i)
        __builtin_nontemporal_store(l4[i * 256 + t], &o4[i * 256 + t]);
}

// ---------------------------------------------------------------------------
// Fallback: original fully fused kernel (used only if no workspace provided).
// ---------------------------------------------------------------------------
__global__ __launch_bounds__(256) void fused_kernel(const float* __restrict__ x,
                                                    const float* __restrict__ params,
                                                    float* __restrict__ out) {
    __shared__ __align__(16) float y[80];
    __shared__ __align__(16) float coef[72];
    __shared__ __align__(16) float tile[5120];

    const int t = threadIdx.x;
    const int g = blockIdx.x * 256 + t;
    const v2f xv = __builtin_nontemporal_load(&((const v2f*)x)[g]);

    if (t < NCLS * 8) {
        const int c = t >> 3;
        const int k = t & 7;
        const float shx = SHK[k], chx = CHK[k];
        float s0r = 1.f, s0i = 0.f, s1r = 0.f, s1i = 0.f;
        #pragma unroll
        for (int l = 0; l < NLAYER; ++l) {
            {
                float n0r = chx * s0r - shx * s1r;
                float n0i = chx * s0i - shx * s1i;
                float n1r = shx * s0r + chx * s1r;
                float n1i = shx * s0i + chx * s1i;
                s0r = n0r; s0i = n0i; s1r = n1r; s1i = n1i;
            }
            {
                float th = 0.5f * params[(c * NLAYER + l) * 3 + 0];
                float st, ct; __sincosf(th, &st, &ct);
                float n0r = s0r * ct + s0i * st;
                float n0i = s0i * ct - s0r * st;
                float n1r = s1r * ct - s1i * st;
                float n1i = s1i * ct + s1r * st;
                s0r = n0r; s0i = n0i; s1r = n1r; s1i = n1i;
            }
            {
                float th = 0.5f * params[(c * NLAYER + l) * 3 + 1];
                float sh, ch; __sincosf(th, &sh, &ch);
                float n0r = ch * s0r - sh * s1r;
                float n0i = ch * s0i - sh * s1i;
                float n1r = sh * s0r + ch * s1r;
                float n1i = sh * s0i + ch * s1i;
                s0r = n0r; s0i = n0i; s1r = n1r; s1i = n1i;
            }
            {
                float th = 0.5f * params[(c * NLAYER + l) * 3 + 2];
                float st, ct; __sincosf(th, &st, &ct);
                float n0r = s0r * ct + s0i * st;
                float n0i = s0i * ct - s0r * st;
                float n1r = s1r * ct - s1i * st;
                float n1i = s1i * ct + s1r * st;
                s0r = n0r; s0i = n0i; s1r = n1r; s1i = n1i;
            }
        }
        y[t] = s0r * s0r + s0i * s0i;
    }
    __syncthreads();

    if (t < NCLS * 7) {
        const int c = t / 7;
        const int j = t % 7;
        float acc = 0.f;
        #pragma unroll
        for (int k = 0; k < 8; ++k) {
            float w;
            if (j == 0)       w = 0.125f;
            else if (j <= 3)  w = 0.25f * CT8[(j * k) & 7];
            else              w = 0.25f * ST8[((j - 3) * k) & 7];
            acc += y[c * 8 + k] * w;
        }
        coef[c * 7 + j] = acc;
    }
    __syncthreads();

    float cf[NCLS * 7];
    #pragma unroll
    for (int i = 0; i < NCLS * 7; ++i)
        cf[i] = __int_as_float(
            __builtin_amdgcn_readfirstlane(__float_as_int(coef[i])));

    const float px[2] = {xv.x, xv.y};
    float r[20];
    #pragma unroll
    for (int p = 0; p < 2; ++p) {
        float s1, c1;
        __sincosf(px[p], &s1, &c1);
        const float c2 = 2.f * c1 * c1 - 1.f;
        const float s2 = 2.f * s1 * c1;
        const float c3 = c1 * c2 - s1 * s2;
        const float s3 = s1 * c2 + c1 * s2;
        #pragma unroll
        for (int c = 0; c < NCLS; ++c) {
            const float* f = &cf[c * 7];
            r[p * 10 + c] = f[0] + f[1] * c1 + f[2] * c2 + f[3] * c3
                                 + f[4] * s1 + f[5] * s2 + f[6] * s3;
        }
    }

    v4f* wb = (v4f*)&tile[t * 20];
    #pragma unroll
    for (int i = 0; i < 5; ++i) wb[i] = ((const v4f*)r)[i];

    __syncthreads();

    v4f* o4 = (v4f*)out + (size_t)blockIdx.x * 1280;
    const v4f* l4 = (const v4f*)tile;
    #pragma unroll
    for (int i = 0; i < 5; ++i)
        __builtin_nontemporal_store(l4[i * 256 + t], &o4[i * 256 + t]);
}

extern "C" void kernel_launch(void* const* d_in, const int* in_sizes, int n_in,
                              void* d_out, int out_size, void* d_ws, size_t ws_size,
                              hipStream_t stream) {
    const float* x      = (const float*)d_in[0];   // [512*3*32*32] fp32
    const float* params = (const float*)d_in[1];   // [10*3*3] fp32
    float* out          = (float*)d_out;           // [512*3072*10] fp32

    const int pairs  = NPIX / 2;                   // 786,432 pixel pairs
    const int blocks = pairs / 256;                // 3,072 (exact)

    if (d_ws != nullptr && ws_size >= 512) {
        float* coef = (float*)d_ws;                // 280 B of workspace
        coef_kernel<<<1, 128, 0, stream>>>(params, coef);
        pix_kernel<<<blocks, 256, 0, stream>>>(x, coef, out);
    } else {
        // no workspace available -> original fused path
        fused_kernel<<<blocks, 256, 0, stream>>>(x, params, out);
    }
}

// Round 2
// 79.983 us; speedup vs baseline: 1.0532x; 1.0532x over previous
//
#include <hip/hip_runtime.h>
#include <math.h>

// Problem constants
#define NPIX   (512 * 3072)     // 1,572,864 pixels (= flat x length)
#define NCLS   10
#define NLAYER 3

typedef float v2f __attribute__((ext_vector_type(2)));
typedef float v4f __attribute__((ext_vector_type(4)));

// sin/cos(k*pi/8), k=0..7  (half-angles of the 8 DFT sample points x_k = k*pi/4)
__device__ __constant__ float SHK[8] = {
    0.0f, 0.38268343236f, 0.70710678119f, 0.92387953251f,
    1.0f, 0.92387953251f, 0.70710678119f, 0.38268343236f };
__device__ __constant__ float CHK[8] = {
    1.0f, 0.92387953251f, 0.70710678119f, 0.38268343236f,
    0.0f, -0.38268343236f, -0.70710678119f, -0.92387953251f };
// cos/sin(i*pi/4), i=0..7 (DFT twiddles)
__device__ __constant__ float CT8[8] = {
    1.0f, 0.70710678119f, 0.0f, -0.70710678119f,
    -1.0f, -0.70710678119f, 0.0f, 0.70710678119f };
__device__ __constant__ float ST8[8] = {
    0.0f, 0.70710678119f, 1.0f, 0.70710678119f,
    0.0f, -0.70710678119f, -1.0f, -0.70710678119f };

// ---------------------------------------------------------------------------
// |s0(x)|^2 of the 3-layer re-uploading circuit is band-limited to the 3rd
// harmonic of x: out[p][c] = a0 + sum_m am cos(mx) + bm sin(mx).
// 7 coefficients/class, recovered exactly by an 8-point DFT of the circuit
// sampled at x_k = k*pi/4.
//
// R2 structure: single launch (R1's split kernel was net -2 µs: the extra
// serialized launch cost more than the removed phases saved).
//   phase 1: threads 0..79 run the circuit at sample k          -> y[80]
//   phase 2: threads 0..69 table-weighted 8-pt DFT              -> coef[70]
//   phase 3: coefs -> SGPRs; each thread computes 4 pixels (2 pixel-pairs,
//            pass A = pair t, pass B = pair t+256) and streams each 20 KB
//            half-tile out as contiguous wave-wide float4 REGULAR stores
//            (nt flag dropped this round: the only store-throughput unknown;
//            the harness fill proves cached stores sustain ~6 TB/s).
// 1536 blocks (was 3072): halves redundant coef work + block launches.
// LDS ~20.6 KB -> 7 blocks/CU, unchanged vs baseline.
// ---------------------------------------------------------------------------

__device__ __forceinline__ void recon(const v2f xv, const float* __restrict__ cf,
                                      float* __restrict__ r) {
    const float px[2] = {xv.x, xv.y};
    #pragma unroll
    for (int p = 0; p < 2; ++p) {
        float s1, c1;
        __sincosf(px[p], &s1, &c1);             // x in [0,1): fast path OK
        const float c2 = 2.f * c1 * c1 - 1.f;
        const float s2 = 2.f * s1 * c1;
        const float c3 = c1 * c2 - s1 * s2;
        const float s3 = s1 * c2 + c1 * s2;
        #pragma unroll
        for (int c = 0; c < NCLS; ++c) {
            const float* f = &cf[c * 7];
            r[p * 10 + c] = f[0] + f[1] * c1 + f[2] * c2 + f[3] * c3
                                 + f[4] * s1 + f[5] * s2 + f[6] * s3;
        }
    }
}

__global__ __launch_bounds__(256) void fused_kernel(const float* __restrict__ x,
                                                    const float* __restrict__ params,
                                                    float* __restrict__ out) {
    __shared__ __align__(16) float y[80];       // y[c*8 + k]
    __shared__ __align__(16) float coef[72];    // [class][7]
    __shared__ __align__(16) float tile[5120];  // 20 KB output staging (reused A/B)

    const int t = threadIdx.x;
    const int b = blockIdx.x;

    // two pixel-pairs per thread; both loads issued early (read-once -> nt)
    const int pairA = b * 512 + t;
    const v2f xa = __builtin_nontemporal_load(&((const v2f*)x)[pairA]);
    const v2f xb = __builtin_nontemporal_load(&((const v2f*)x)[pairA + 256]);

    // ---- phase 1: circuit eval at the 8 sample angles per class ----
    if (t < NCLS * 8) {
        const int c = t >> 3;
        const int k = t & 7;
        const float shx = SHK[k], chx = CHK[k];   // Ry(x_k) half-angle sin/cos

        float s0r = 1.f, s0i = 0.f, s1r = 0.f, s1i = 0.f;

        #pragma unroll
        for (int l = 0; l < NLAYER; ++l) {
            // Ry(x_k)
            {
                float n0r = chx * s0r - shx * s1r;
                float n0i = chx * s0i - shx * s1i;
                float n1r = shx * s0r + chx * s1r;
                float n1i = shx * s0i + chx * s1i;
                s0r = n0r; s0i = n0i; s1r = n1r; s1i = n1i;
            }
            // Rz(g0): s0 *= e^{-i th}, s1 *= e^{+i th}
            {
                float th = 0.5f * params[(c * NLAYER + l) * 3 + 0];
                float st, ct;
                __sincosf(th, &st, &ct);
                float n0r = s0r * ct + s0i * st;
                float n0i = s0i * ct - s0r * st;
                float n1r = s1r * ct - s1i * st;
                float n1i = s1i * ct + s1r * st;
                s0r = n0r; s0i = n0i; s1r = n1r; s1i = n1i;
            }
            // Ry(g1)
            {
                float th = 0.5f * params[(c * NLAYER + l) * 3 + 1];
                float sh, ch;
                __sincosf(th, &sh, &ch);
                float n0r = ch * s0r - sh * s1r;
                float n0i = ch * s0i - sh * s1i;
                float n1r = sh * s0r + ch * s1r;
                float n1i = sh * s0i + ch * s1i;
                s0r = n0r; s0i = n0i; s1r = n1r; s1i = n1i;
            }
            // Rz(g2)
            {
                float th = 0.5f * params[(c * NLAYER + l) * 3 + 2];
                float st, ct;
                __sincosf(th, &st, &ct);
                float n0r = s0r * ct + s0i * st;
                float n0i = s0i * ct - s0r * st;
                float n1r = s1r * ct - s1i * st;
                float n1i = s1i * ct + s1r * st;
                s0r = n0r; s0i = n0i; s1r = n1r; s1i = n1i;
            }
        }
        y[t] = s0r * s0r + s0i * s0i;           // t == c*8 + k
    }
    __syncthreads();

    // ---- phase 2: table-weighted 8-point DFT -> 7 coefficients/class ----
    if (t < NCLS * 7) {
        const int c = t / 7;
        const int j = t % 7;
        float acc = 0.f;
        #pragma unroll
        for (int k = 0; k < 8; ++k) {
            float w;
            if (j == 0)       w = 0.125f;
            else if (j <= 3)  w = 0.25f * CT8[(j * k) & 7];
            else              w = 0.25f * ST8[((j - 3) * k) & 7];
            acc += y[c * 8 + k] * w;
        }
        coef[c * 7 + j] = acc;
    }
    __syncthreads();

    // ---- phase 3: per-pixel reconstruction, two passes ----
    // block-uniform coefficients -> SGPRs via readfirstlane (broadcast LDS
    // read is conflict-free; frees ~70 VGPRs)
    float cf[NCLS * 7];
    #pragma unroll
    for (int i = 0; i < NCLS * 7; ++i)
        cf[i] = __int_as_float(
            __builtin_amdgcn_readfirstlane(__float_as_int(coef[i])));

    v4f* o4 = (v4f*)out + (size_t)b * 2560;     // 10240 floats/block
    const v4f* l4 = (const v4f*)tile;
    float r[20];

    // pass A: pairs [b*512, b*512+256)
    recon(xa, cf, r);
    {
        v4f* wb = (v4f*)&tile[t * 20];          // 80 B lane stride: <=2-way, free
        #pragma unroll
        for (int i = 0; i < 5; ++i) wb[i] = ((const v4f*)r)[i];
    }
    __syncthreads();
    #pragma unroll
    for (int i = 0; i < 5; ++i)
        o4[i * 256 + t] = l4[i * 256 + t];      // regular cached store
    __syncthreads();                            // all reads of tile done

    // pass B: pairs [b*512+256, b*512+512)
    recon(xb, cf, r);
    {
        v4f* wb = (v4f*)&tile[t * 20];
        #pragma unroll
        for (int i = 0; i < 5; ++i) wb[i] = ((const v4f*)r)[i];
    }
    __syncthreads();
    #pragma unroll
    for (int i = 0; i < 5; ++i)
        o4[1280 + i * 256 + t] = l4[i * 256 + t];
}

extern "C" void kernel_launch(void* const* d_in, const int* in_sizes, int n_in,
                              void* d_out, int out_size, void* d_ws, size_t ws_size,
                              hipStream_t stream) {
    const float* x      = (const float*)d_in[0];   // [512*3*32*32] fp32
    const float* params = (const float*)d_in[1];   // [10*3*3] fp32
    float* out          = (float*)d_out;           // [512*3072*10] fp32
    (void)d_ws; (void)ws_size;

    const int blocks = NPIX / 1024;                // 4 pixels/thread -> 1536
    fused_kernel<<<blocks, 256, 0, stream>>>(x, params, out);
}